// Round 4
// baseline (1431.688 us; speedup 1.0000x reference)
//
#include <hip/hip_runtime.h>
#include <hip/hip_bf16.h>

// Problem constants
constexpr int NB  = 16;     // batch
constexpr int DIN = 512;    // channels
constexpr int TT  = 4096;   // time
constexpr int NCB = 9;      // codebooks
constexpr int KK  = 1024;   // entries per codebook

// output layout (FLOAT32: codes, latent, closs, bloss) — round-2 postmortem.
constexpr size_t OUT_LAT   = (size_t)NB * NCB * TT;            // 589824
constexpr size_t OUT_CLOSS = OUT_LAT + (size_t)NB * DIN * TT;  // 34144256

// LDS strides
constexpr int SRES = 514;
constexpr int SWIN = 516;

// Scratch as __device__ globals (round-0 postmortem: never trust ws_size).
__device__ __align__(16) float g_cbn [NCB * KK * 8];
__device__ __align__(16) float g_c2  [NCB * KK];
__device__ __align__(16) float g_win [NCB * 8 * DIN];   // [i][o][c]
__device__ __align__(16) float g_wout[NCB * DIN * 8];   // [i][c][d]
__device__ double g_loss;

// square with forced separate rounding (blocks -ffp-contract=fast fusing the
// mul into a following add — numpy rounds every square before summing)
__device__ __forceinline__ float sqf(float x) {
  float r = x * x;
  asm volatile("" : "+v"(r));
  return r;
}

// ---------- prep: weight-norm for in_proj ----------
// EXACT numpy pairwise_sum(n=512) mirror for ||v||: split 256+256 -> 128+128
// each; 128-block = 8 scalar accumulators r[j] += s[8m+j] (16 sequential
// adds), tree ((r0+r1)+(r2+r3))+((r4+r5)+(r6+r7)); blocks (B0+B1)+(B2+B3).
// Round-3 postmortem: previous 16-lane grouping was the prime flip suspect.
__global__ void prep_win_k(const float* __restrict__ in_v, const float* __restrict__ in_g) {
  const int r = blockIdx.x * 64 + threadIdx.x;  // i*8 + o, < 72
  if (r >= NCB * 8) return;
  const float* v = in_v + (size_t)r * DIN;
  float blk[4];
#pragma unroll
  for (int bb = 0; bb < 4; ++bb) {
    const float* a = v + bb * 128;
    float r8[8];
#pragma unroll
    for (int j = 0; j < 8; ++j) r8[j] = sqf(a[j]);
#pragma unroll
    for (int m = 1; m < 16; ++m)
#pragma unroll
      for (int j = 0; j < 8; ++j) r8[j] += sqf(a[m * 8 + j]);
    blk[bb] = ((r8[0] + r8[1]) + (r8[2] + r8[3])) + ((r8[4] + r8[5]) + (r8[6] + r8[7]));
  }
  const float total = (blk[0] + blk[1]) + (blk[2] + blk[3]);
  const float nrm = sqrtf(total);               // IEEE sqrt (HIP default precise)
  const float g = in_g[r];
  float* w = g_win + (size_t)r * DIN;
  for (int c = 0; c < DIN; ++c) w[c] = (g * v[c]) / nrm;  // np: (g*v) rounds, then /
}

// ---------- prep: weight-norm for out_proj (n=8: np 8-acc zero-loop tree) ----------
__global__ void prep_wout_k(const float* __restrict__ out_v, const float* __restrict__ out_g) {
  const int row = blockIdx.x * 256 + threadIdx.x;  // i*512 + c, < 4608
  const float* v = out_v + (size_t)row * 8;
  float q[8];
#pragma unroll
  for (int d = 0; d < 8; ++d) q[d] = sqf(v[d]);
  const float nrm = sqrtf(((q[0] + q[1]) + (q[2] + q[3])) + ((q[4] + q[5]) + (q[6] + q[7])));
  const float g = out_g[row];
  float* w = g_wout + (size_t)row * 8;
#pragma unroll
  for (int d = 0; d < 8; ++d) w[d] = (g * v[d]) / nrm;
}

// ---------- prep: normalized codebooks + squared norms; zero loss ----------
__global__ void prep_cbn_k(const float* __restrict__ cb) {
  const int row = blockIdx.x * 256 + threadIdx.x;  // i*1024 + k, < 9216
  const float* v = cb + (size_t)row * 8;
  float q[8];
#pragma unroll
  for (int d = 0; d < 8; ++d) q[d] = sqf(v[d]);
  float nrm = sqrtf(((q[0] + q[1]) + (q[2] + q[3])) + ((q[4] + q[5]) + (q[6] + q[7])));
  nrm = fmaxf(nrm, 1e-12f);
  float cn[8];
#pragma unroll
  for (int d = 0; d < 8; ++d) { cn[d] = v[d] / nrm; g_cbn[(size_t)row * 8 + d] = cn[d]; }
  float s2[8];
#pragma unroll
  for (int d = 0; d < 8; ++d) s2[d] = sqf(cn[d]);
  g_c2[row] = ((s2[0] + s2[1]) + (s2[2] + s2[3])) + ((s2[4] + s2[5]) + (s2[6] + s2[7]));
  if (row == 0) g_loss = 0.0;
}

// ---------- main fused RVQ chain ----------
__global__ __launch_bounds__(256, 3)
void rvq_main_k(const float* __restrict__ z, const float* __restrict__ in_b,
                const float* __restrict__ out_b, const float* __restrict__ cb,
                float* __restrict__ out) {
  __shared__ __align__(16) float s_res[16 * SRES];  // residual [col][c]
  __shared__ __align__(16) float s_win[8 * SWIN];   // W_in rows [o][c]
  __shared__ float s_ze[128];   // z_e [d][col]
  __shared__ float s_en[128];   // enc_n [d][col]
  __shared__ float s_s[16];     // sum(enc_n^2) per col
  __shared__ float s_cd[256];   // candidate dists [ksub][col]
  __shared__ int   s_ck[256];   // candidate ks
  __shared__ float s_zq[128];   // z_q_st [d][col]

  const int tid = threadIdx.x;
  const int col = tid & 15;
  const int grp = tid >> 4;
  const int b   = blockIdx.x >> 8;
  const int t0  = (blockIdx.x & 255) << 4;

  // init: residual = z in LDS; latent accumulator lr = 0 in registers.
  // (reference accumulates latent per step in f32 — mirror exactly, don't
  // reconstruct as z - r_final)
  float lr[32];
  {
    const float* zb = z + (size_t)b * DIN * TT + t0 + col;
#pragma unroll
    for (int j = 0; j < 32; ++j) {
      const int c = grp + (j << 4);
      s_res[col * SRES + c] = zb[(size_t)c * TT];
      lr[j] = 0.0f;
    }
  }

  float loss_acc = 0.0f;

  for (int i = 0; i < NCB; ++i) {
    // ---- stage W_in into LDS (padded rows)
    {
      const float4* gw = (const float4*)(g_win + i * 4096);
#pragma unroll
      for (int q = 0; q < 4; ++q) {
        const int e = (q * 256 + tid) * 4;
        *(float4*)(s_win + (e >> 9) * SWIN + (e & 511)) = gw[q * 256 + tid];
      }
    }
    __syncthreads();  // orders prev-D s_res writes vs A1 reads

    // ---- A1: in-proj. numpy einsum SOP path: out[t] += W[o,c]*r[c,t], FMA,
    // c ascending — a single sequential fmaf chain per (o,t).
    if (tid < 128) {
      const int o = tid >> 4, cc = tid & 15;
      const float2* wr = (const float2*)(s_win + o * SWIN);
      const float2* rr = (const float2*)(s_res + cc * SRES);
      float acc = 0.0f;
#pragma unroll 8
      for (int h = 0; h < 256; ++h) {
        const float2 w = wr[h];
        const float2 r = rr[h];
        acc = fmaf(w.x, r.x, acc);
        acc = fmaf(w.y, r.y, acc);
      }
      s_ze[o * 16 + cc] = acc + in_b[i * 8 + o];  // bias added after (np.add)
    }
    __syncthreads();

    // ---- A2: normalize (np: rounded squares, pairwise-8 tree, IEEE div, max eps)
    if (tid < 16) {
      float e[8], q[8];
#pragma unroll
      for (int d = 0; d < 8; ++d) { e[d] = s_ze[d * 16 + tid]; q[d] = sqf(e[d]); }
      float nrm = sqrtf(((q[0] + q[1]) + (q[2] + q[3])) + ((q[4] + q[5]) + (q[6] + q[7])));
      nrm = fmaxf(nrm, 1e-12f);
      float en[8], s2[8];
#pragma unroll
      for (int d = 0; d < 8; ++d) { en[d] = e[d] / nrm; s_en[d * 16 + tid] = en[d]; s2[d] = sqf(en[d]); }
      s_s[tid] = ((s2[0] + s2[1]) + (s2[2] + s2[3])) + ((s2[4] + s2[5]) + (s2[6] + s2[7]));
    }
    __syncthreads();

    // ---- B: distance scan, k = 16j+grp per thread.
    // np: (2*enc_n)@cb_n.T via sgemm (FMA k-ascending). Exact ×2 commutes with
    // rounding, so dot2 == 2*dot bitwise; dist = (s - dot2) + c2 == fmaf(-2,dot,s)+c2.
    {
      const float en0 = s_en[0 * 16 + col], en1 = s_en[1 * 16 + col];
      const float en2 = s_en[2 * 16 + col], en3 = s_en[3 * 16 + col];
      const float en4 = s_en[4 * 16 + col], en5 = s_en[5 * 16 + col];
      const float en6 = s_en[6 * 16 + col], en7 = s_en[7 * 16 + col];
      const float sv = s_s[col];
      const float* cp  = g_cbn + (size_t)i * 8192 + (grp << 3);
      const float* c2p = g_c2 + i * KK + grp;
      float dmin = 3.402823466e38f; int kmin = 0;
#pragma unroll 4
      for (int j = 0; j < 64; ++j) {
        const float4 c0 = *(const float4*)(cp + (j << 7));
        const float4 c1 = *(const float4*)(cp + (j << 7) + 4);
        const float cc2 = c2p[j << 4];
        float dot = 0.0f;
        dot = fmaf(en0, c0.x, dot); dot = fmaf(en1, c0.y, dot);
        dot = fmaf(en2, c0.z, dot); dot = fmaf(en3, c0.w, dot);
        dot = fmaf(en4, c1.x, dot); dot = fmaf(en5, c1.y, dot);
        dot = fmaf(en6, c1.z, dot); dot = fmaf(en7, c1.w, dot);
        const float dist = fmaf(-2.0f, dot, sv) + cc2;
        if (dist < dmin) { dmin = dist; kmin = (j << 4) + grp; }
      }
      s_cd[grp * 16 + col] = dmin;
      s_ck[grp * 16 + col] = kmin;
    }
    __syncthreads();

    // ---- B-red: argmin per column (np first-min tie rule), codes + z_q_st + loss
    if (tid < 16) {
      float bd = s_cd[tid]; int bk = s_ck[tid];
#pragma unroll
      for (int ks = 1; ks < 16; ++ks) {
        const float d2 = s_cd[ks * 16 + tid]; const int k2 = s_ck[ks * 16 + tid];
        if (d2 < bd || (d2 == bd && k2 < bk)) { bd = d2; bk = k2; }
      }
      out[((size_t)b * NCB + i) * TT + t0 + tid] = (float)bk;
      const float* cr = cb + ((size_t)i * KK + bk) * 8;  // RAW codebook row
#pragma unroll
      for (int d = 0; d < 8; ++d) {
        const float zq = cr[d];
        const float ze = s_ze[d * 16 + tid];
        const float df = ze - zq;
        loss_acc = fmaf(df, df, loss_acc);         // loss precision uncritical (2% thr)
        s_zq[d * 16 + tid] = ze + (zq - ze);       // STE rounding mirrored
      }
    }
    __syncthreads();

    // ---- D: out-proj (einsum SOP: FMA ascending d) + latent & residual update
    {
      const float q0 = s_zq[0 * 16 + col], q1 = s_zq[1 * 16 + col];
      const float q2 = s_zq[2 * 16 + col], q3 = s_zq[3 * 16 + col];
      const float q4 = s_zq[4 * 16 + col], q5 = s_zq[5 * 16 + col];
      const float q6 = s_zq[6 * 16 + col], q7 = s_zq[7 * 16 + col];
      const float* gw = g_wout + (size_t)i * 4096;
      const float* ob = out_b + i * DIN;
#pragma unroll 4
      for (int j = 0; j < 32; ++j) {
        const int c = grp + (j << 4);
        const float4 w0 = *(const float4*)(gw + c * 8);
        const float4 w1 = *(const float4*)(gw + c * 8 + 4);
        float dot = 0.0f;
        dot = fmaf(w0.x, q0, dot); dot = fmaf(w0.y, q1, dot);
        dot = fmaf(w0.z, q2, dot); dot = fmaf(w0.w, q3, dot);
        dot = fmaf(w1.x, q4, dot); dot = fmaf(w1.y, q5, dot);
        dot = fmaf(w1.z, q6, dot); dot = fmaf(w1.w, q7, dot);
        const float lat = dot + ob[c];     // einsum + bias (one rounded add)
        lr[j] += lat;                      // latent += lat_i  (np per-step f32 add)
        s_res[col * SRES + c] -= lat;      // residual -= lat_i
      }
    }
    // no barrier: next stage writes only s_win (disjoint)
  }

  // latent output (exact per-step accumulation)
  {
    float* lat = out + OUT_LAT;
#pragma unroll
    for (int j = 0; j < 32; ++j) {
      const int c = grp + (j << 4);
      lat[((size_t)b * DIN + c) * TT + t0 + col] = lr[j];
    }
  }

  // loss reduce (nonzero only lanes 0..15 of wave 0), one atomic per block
  if (tid < 64) {
    float v = loss_acc;
#pragma unroll
    for (int off = 32; off; off >>= 1) v += __shfl_down(v, off);
    if (tid == 0) atomicAdd(&g_loss, (double)v);
  }
}

// ---------- epilogue: finalize scalar losses ----------
__global__ void rvq_epi_k(float* __restrict__ out) {
  const float m = (float)(g_loss / 524288.0);  // B*D_CB*T
  out[OUT_CLOSS]     = m;
  out[OUT_CLOSS + 1] = m;
}

extern "C" void kernel_launch(void* const* d_in, const int* in_sizes, int n_in,
                              void* d_out, int out_size, void* d_ws, size_t ws_size,
                              hipStream_t stream) {
  const float* z     = (const float*)d_in[0];
  const float* in_v  = (const float*)d_in[1];
  const float* in_g  = (const float*)d_in[2];
  const float* in_b  = (const float*)d_in[3];
  const float* out_v = (const float*)d_in[4];
  const float* out_g = (const float*)d_in[5];
  const float* out_b = (const float*)d_in[6];
  const float* cb    = (const float*)d_in[7];
  float* out = (float*)d_out;
  (void)d_ws; (void)ws_size;

  prep_win_k <<<2, 64, 0, stream>>>(in_v, in_g);
  prep_wout_k<<<18, 256, 0, stream>>>(out_v, out_g);
  prep_cbn_k <<<36, 256, 0, stream>>>(cb);
  rvq_main_k <<<4096, 256, 0, stream>>>(z, in_b, out_b, cb, out);
  rvq_epi_k  <<<1, 1, 0, stream>>>(out);
}